// Round 15
// baseline (20199.559 us; speedup 1.0000x reference)
//
#include <hip/hip_runtime.h>
#include <hip/hip_bf16.h>

#define TT 256
#define D 1024
#define BD (128 * 1024)
#define NSL 43        // col-slices per layer (42 x 24 cols + 1 x 16)
#define NWG (3 * NSL) // 129
#define ROWLEN 1048

typedef __attribute__((ext_vector_type(8))) short bf16x8;
typedef __attribute__((ext_vector_type(4))) float f32x4;

__device__ __forceinline__ unsigned short f2bf(float f) {
    __hip_bfloat16 h = __float2bfloat16(f);
    return *reinterpret_cast<unsigned short*>(&h);
}
__device__ __forceinline__ float bf2f(unsigned short u) {
    unsigned v = (unsigned)u << 16;
    return __builtin_bit_cast(float, v);
}

__global__ __launch_bounds__(256) void cvt_f32_bf16(const float* __restrict__ in,
                                                    unsigned short* __restrict__ out, int n) {
    int i = (blockIdx.x * 256 + threadIdx.x) * 8;
    if (i + 8 <= n) {
        float4 a = *(const float4*)(in + i);
        float4 b = *(const float4*)(in + i + 4);
        unsigned short t[8] = { f2bf(a.x), f2bf(a.y), f2bf(a.z), f2bf(a.w),
                                f2bf(b.x), f2bf(b.y), f2bf(b.z), f2bf(b.w) };
        *(uint4*)(out + i) = *(const uint4*)t;
    }
}

#define SB __builtin_amdgcn_sched_barrier(0)
#define AGLD(p) __hip_atomic_load((p), __ATOMIC_RELAXED, __HIP_MEMORY_SCOPE_AGENT)
#define AGST(p, v) __hip_atomic_store((p), (v), __ATOMIC_RELAXED, __HIP_MEMORY_SCOPE_AGENT)
#define MF(a, b, c) __builtin_amdgcn_mfma_f32_16x16x32_bf16(a, b, c, 0, 0, 0)

// Persistent dataflow dilated-GRU, HYBRID weights: Whh LDS-stationary (24 cols),
// Wih streamed bf16 from L2 (read-only, L2-resident). 129 WGs => A-broadcast
// traffic 66 MB/step (was 130). 32-slot rings + acquire fence every 16 steps.
__global__ __launch_bounds__(256, 1) void dgru_hybrid(
    const unsigned short* __restrict__ xbf,
    const unsigned short* __restrict__ Wih_bf,  // [3][3D][D] bf16
    const float* __restrict__ Whh,              // [3][3D][D] f32
    const float* __restrict__ bih, const float* __restrict__ bhh,
    unsigned short* __restrict__ ring_bf,   // [3][32][BD]
    float* __restrict__ ring_f,             // [3][32][BD]
    unsigned short* __restrict__ hin_ring,  // [2][32][BD]
    float* __restrict__ out,
    unsigned* __restrict__ prog)
{
    __shared__ unsigned short wlds[72 * ROWLEN];  // Whh: 3 mats x <=24 cols

    const int p = blockIdx.x;
    const int layer = p / NSL;
    const int u     = p % NSL;
    const int ncols = (u < 42) ? 24 : 16;
    const int c0    = u * 24;

    // ---- one-time: Whh slice fp32 -> bf16 -> LDS (stationary)
    {
        const float* w1 = Whh + (size_t)layer * 3 * D * D;
        const int nrows = 3 * ncols;
        for (int rid = 0; rid < nrows; ++rid) {
            int g = rid / ncols;
            int c = rid - g * ncols;
            const float* src = w1 + ((size_t)g * D + c0 + c) * D + threadIdx.x * 4;
            float4 v = *(const float4*)src;
            ushort4 o = { f2bf(v.x), f2bf(v.y), f2bf(v.z), f2bf(v.w) };
            *(ushort4*)&wlds[rid * ROWLEN + threadIdx.x * 4] = o;
        }
        __syncthreads();
    }

    const int tid  = threadIdx.x;
    const int wave = tid >> 6;
    const int lane = tid & 63;
    const int r15  = lane & 15;
    const int kq   = lane >> 4;
    const int kq8  = kq * 8;

    // two 16-col tiles; clamp invalid lanes (stores masked)
    int  cc[2];  bool cvalid[2];  int col[2];
    #pragma unroll
    for (int ct = 0; ct < 2; ++ct) {
        int c = ct * 16 + r15;
        cvalid[ct] = c < ncols;
        cc[ct] = cvalid[ct] ? c : (ncols - 1);
        col[ct] = c0 + cc[ct];
    }

    float bs0[2], bs1[2], bi2c[2], bh2c[2];
    #pragma unroll
    for (int ct = 0; ct < 2; ++ct) {
        bs0[ct]  = bih[layer * 3 * D + col[ct]] + bhh[layer * 3 * D + col[ct]];
        bs1[ct]  = bih[layer * 3 * D + D + col[ct]] + bhh[layer * 3 * D + D + col[ct]];
        bi2c[ct] = bih[layer * 3 * D + 2 * D + col[ct]];
        bh2c[ct] = bhh[layer * 3 * D + 2 * D + col[ct]];
    }

    // B pointers: LDS Whh [g][ct], streamed global Wih [g][ct]
    const unsigned short* bpL[3][2];
    const unsigned short* bpS[3][2];
    const unsigned short* Wih_l = Wih_bf + (size_t)layer * 3 * D * D;
    #pragma unroll
    for (int g = 0; g < 3; ++g)
        #pragma unroll
        for (int ct = 0; ct < 2; ++ct) {
            bpL[g][ct] = wlds + (size_t)(g * ncols + cc[ct]) * ROWLEN + kq8;
            bpS[g][ct] = Wih_l + ((size_t)g * D + col[ct]) * D + kq8;
        }

    const int arow_off0 = (wave * 32 + r15) * D + kq8;
    const int arow_off1 = arow_off0 + 16 * D;

    const int dil = 1 << layer;

    unsigned* pr0 = prog;
    unsigned* pr1 = prog + 64;
    unsigned* pr2 = prog + 128;
    unsigned* myflag = prog + layer * 64 + u;
    const int fi = (lane < NSL) ? lane : (NSL - 1);

    for (int t = 0; t < TT; ++t) {
        // thresholds: hin-ready / hprev-ready / 32-slot back-pressure
        int th1, th2, th3; unsigned *a1, *a2, *a3;
        if (layer == 0)      { a1 = pr0; th1 = t;     a2 = pr1; th2 = t - 30; a3 = pr2; th3 = 0;      }
        else if (layer == 1) { a1 = pr0; th1 = t + 1; a2 = pr1; th2 = t - 1;  a3 = pr2; th3 = t - 30; }
        else                 { a1 = pr1; th1 = t + 1; a2 = pr2; th2 = t - 3;  a3 = pr2; th3 = 0;      }

        if (wave == 0) {
            for (;;) {
                bool ok = true;
                if (th1 > 0) ok = ok && (int)AGLD(a1 + fi) >= th1;
                if (th2 > 0) ok = ok && (int)AGLD(a2 + fi) >= th2;
                if (th3 > 0) ok = ok && (int)AGLD(a3 + fi) >= th3;
                if (__all(ok)) break;
                __builtin_amdgcn_s_sleep(1);
            }
            if ((t & 15) == 0)
                __builtin_amdgcn_fence(__ATOMIC_ACQUIRE, "agent");  // 16 < 32 - dil
        }
        __syncthreads();

        const unsigned short* hinb = layer ? hin_ring + (size_t)((layer - 1) * 32 + (t & 31)) * BD
                                           : xbf + (size_t)t * BD;
        const int rs = (t + 32 - dil) & 31, wsl = t & 31;
        const unsigned short* hprevb = ring_bf + (size_t)(layer * 32 + rs) * BD;
        const float*  hprevf = ring_f + (size_t)(layer * 32 + rs) * BD;
        float*        houtf  = ring_f + (size_t)(layer * 32 + wsl) * BD;
        unsigned short* houtb = ring_bf + (size_t)(layer * 32 + wsl) * BD;

        // ---- epilogue operand prefetch (plain; freshness by fence-interval)
        float hpv[2][2][4], rsv[2][2][4];
        #pragma unroll
        for (int ct = 0; ct < 2; ++ct)
            #pragma unroll
            for (int rtl = 0; rtl < 2; ++rtl)
                #pragma unroll
                for (int q = 0; q < 4; ++q) {
                    const int row = wave * 32 + rtl * 16 + kq * 4 + q;
                    const size_t idx = (size_t)row * D + col[ct];
                    hpv[ct][rtl][q] = hprevf[idx];
                    rsv[ct][rtl][q] = bf2f(hinb[idx]);
                }

        // acc[rtl][ct][m]: m 0..2 = gi(r,z,n) from streamed Wih; 3..5 = gh from LDS Whh
        f32x4 acc[2][2][6] = {};
        bf16x8 A0[16], A1[16], A2[16];

#define ISSUE1(Av, KS, SL) { \
        Av[(SL) * 4 + 0] = *(const bf16x8*)(hinb   + arow_off0 + (KS) * 32); \
        Av[(SL) * 4 + 1] = *(const bf16x8*)(hprevb + arow_off0 + (KS) * 32); \
        Av[(SL) * 4 + 2] = *(const bf16x8*)(hinb   + arow_off1 + (KS) * 32); \
        Av[(SL) * 4 + 3] = *(const bf16x8*)(hprevb + arow_off1 + (KS) * 32); }
#define ISSUEG(Av, BASE) { ISSUE1(Av, (BASE) + 0, 0) ISSUE1(Av, (BASE) + 1, 1) \
                           ISSUE1(Av, (BASE) + 2, 2) ISSUE1(Av, (BASE) + 3, 3) \
                           SB; }
#define COMPG(Av, BASE) { _Pragma("unroll") for (int kk = 0; kk < 4; ++kk) { \
        bf16x8 WS[3][2], WL[3][2]; \
        _Pragma("unroll") for (int g = 0; g < 3; ++g) \
        _Pragma("unroll") for (int ct = 0; ct < 2; ++ct) { \
            WS[g][ct] = *(const bf16x8*)(bpS[g][ct] + ((BASE) + kk) * 32); \
            WL[g][ct] = *(const bf16x8*)(bpL[g][ct] + ((BASE) + kk) * 32); } \
        bf16x8 h0 = Av[kk * 4 + 0], p0 = Av[kk * 4 + 1]; \
        bf16x8 h1 = Av[kk * 4 + 2], p1 = Av[kk * 4 + 3]; \
        _Pragma("unroll") for (int g = 0; g < 3; ++g) \
        _Pragma("unroll") for (int ct = 0; ct < 2; ++ct) { \
            acc[0][ct][g]     = MF(h0, WS[g][ct], acc[0][ct][g]); \
            acc[1][ct][g]     = MF(h1, WS[g][ct], acc[1][ct][g]); \
            acc[0][ct][3 + g] = MF(p0, WL[g][ct], acc[0][ct][3 + g]); \
            acc[1][ct][3 + g] = MF(p1, WL[g][ct], acc[1][ct][3 + g]); } } \
        SB; }

        ISSUEG(A0, 0);  ISSUEG(A1, 4);  ISSUEG(A2, 8);
        COMPG(A0, 0);   ISSUEG(A0, 12);
        COMPG(A1, 4);   ISSUEG(A1, 16);
        COMPG(A2, 8);   ISSUEG(A2, 20);
        COMPG(A0, 12);  ISSUEG(A0, 24);
        COMPG(A1, 16);  ISSUEG(A1, 28);
        COMPG(A2, 20);
        COMPG(A0, 24);
        COMPG(A1, 28);

        // ---- gates + residual; sc1 stores (MALL-direct, cross-XCD coherent)
        #pragma unroll
        for (int ct = 0; ct < 2; ++ct)
        #pragma unroll
        for (int rtl = 0; rtl < 2; ++rtl)
        #pragma unroll
        for (int q = 0; q < 4; ++q) {
            const int row = wave * 32 + rtl * 16 + kq * 4 + q;
            const size_t idx = (size_t)row * D + col[ct];
            float xr = acc[rtl][ct][0][q] + acc[rtl][ct][3][q] + bs0[ct];
            float xz = acc[rtl][ct][1][q] + acc[rtl][ct][4][q] + bs1[ct];
            float rg = 1.f / (1.f + __expf(-xr));
            float zg = 1.f / (1.f + __expf(-xz));
            float ng = tanhf(acc[rtl][ct][2][q] + bi2c[ct] + rg * (acc[rtl][ct][5][q] + bh2c[ct]));
            float hp = hpv[ct][rtl][q];
            float h  = (1.f - zg) * ng + zg * hp;
            float v = (h + rsv[ct][rtl][q]) * 0.70710678f;
            float y = v > 0.f ? v : 0.2f * v;
            if (cvalid[ct]) {
                AGST(&houtf[idx], h);
                AGST(&houtb[idx], f2bf(h));
                if (layer == 2) {
                    AGST(&out[(size_t)t * BD + idx], y);
                } else {
                    AGST(&hin_ring[(size_t)(layer * 32 + (t & 31)) * BD + idx], f2bf(y));
                }
            }
        }

        asm volatile("s_waitcnt vmcnt(0)");
        __syncthreads();  // all waves' stores MALL-ack'd before publish
        if (tid == 0) {
            __builtin_amdgcn_fence(__ATOMIC_RELEASE, "agent");
            AGST(myflag, (unsigned)(t + 1));
        }
    }
}

extern "C" void kernel_launch(void* const* d_in, const int* in_sizes, int n_in,
                              void* d_out, int out_size, void* d_ws, size_t ws_size,
                              hipStream_t stream) {
    const float* x   = (const float*)d_in[0];
    const float* Wih = (const float*)d_in[1];
    const float* Whh = (const float*)d_in[2];
    const float* bih = (const float*)d_in[3];
    const float* bhh = (const float*)d_in[4];
    float* out = (float*)d_out;

    char* ws = (char*)d_ws;
    size_t off = 0;
    auto alloc = [&](size_t bytes) -> void* {
        void* p = ws + off;
        off += (bytes + 255) & ~(size_t)255;
        return p;
    };

    const int NX = TT * BD;          // 33,554,432
    const int NW = 3 * 3 * D * D;    // 9,437,184
    unsigned short* xbf    = (unsigned short*)alloc((size_t)NX * 2);  // 67 MB
    unsigned short* Wih_bf = (unsigned short*)alloc((size_t)NW * 2);  // 19 MB

    size_t zstart = off;
    unsigned short* ring_bf  = (unsigned short*)alloc((size_t)96 * BD * 2);  // 25 MB
    float*          ring_f   = (float*)alloc((size_t)96 * BD * 4);           // 50 MB
    unsigned short* hin_ring = (unsigned short*)alloc((size_t)64 * BD * 2);  // 17 MB
    unsigned*       prog     = (unsigned*)alloc(1024);
    size_t zbytes = off - zstart;

    cvt_f32_bf16<<<NX / 8 / 256, 256, 0, stream>>>(x, xbf, NX);
    cvt_f32_bf16<<<NW / 8 / 256, 256, 0, stream>>>(Wih, Wih_bf, NW);
    hipMemsetAsync(ws + zstart, 0, zbytes, stream);

    dgru_hybrid<<<NWG, 256, 0, stream>>>(
        xbf, Wih_bf, Whh, bih, bhh,
        ring_bf, ring_f, hin_ring, out,
        prog);
}

// Round 17
// 8296.016 us; speedup vs baseline: 2.4349x; 2.4349x over previous
//
#include <hip/hip_runtime.h>
#include <hip/hip_bf16.h>

#define TT 256
#define D 1024
#define BD (128 * 1024)
#define NSL 40          // col-slices per layer (39 x 26 + 1 x 10)
#define NUNIT (3 * NSL) // 120
#define NWG (2 * NUNIT) // 240
#define KH 512
#define ROWL 520        // 512 + 8 pad elems
#define PBLK 96         // partial bytes per thread (2ct x 6m x 4q bf16)
#define PREG (4 * 64 * PBLK)  // 24,576 B per region (4 waves x 64 lanes)

typedef __attribute__((ext_vector_type(8))) short bf16x8;
typedef __attribute__((ext_vector_type(4))) float f32x4;
typedef unsigned long long ull;

__device__ __forceinline__ unsigned short f2bf(float f) {
    __hip_bfloat16 h = __float2bfloat16(f);
    return *reinterpret_cast<unsigned short*>(&h);
}
__device__ __forceinline__ float bf2f(unsigned short u) {
    unsigned v = (unsigned)u << 16;
    return __builtin_bit_cast(float, v);
}

__global__ __launch_bounds__(256) void cvt_f32_bf16(const float* __restrict__ in,
                                                    unsigned short* __restrict__ out, int n) {
    int i = (blockIdx.x * 256 + threadIdx.x) * 8;
    if (i + 8 <= n) {
        float4 a = *(const float4*)(in + i);
        float4 b = *(const float4*)(in + i + 4);
        unsigned short t[8] = { f2bf(a.x), f2bf(a.y), f2bf(a.z), f2bf(a.w),
                                f2bf(b.x), f2bf(b.y), f2bf(b.z), f2bf(b.w) };
        *(uint4*)(out + i) = *(const uint4*)t;
    }
}

#define SB __builtin_amdgcn_sched_barrier(0)
#define AGLD(p) __hip_atomic_load((p), __ATOMIC_RELAXED, __HIP_MEMORY_SCOPE_AGENT)
#define AGST(p, v) __hip_atomic_store((p), (v), __ATOMIC_RELAXED, __HIP_MEMORY_SCOPE_AGENT)
#define MF(a, b, c) __builtin_amdgcn_mfma_f32_16x16x32_bf16(a, b, c, 0, 0, 0)

// K-split persistent dataflow dilated-GRU.
// 240 WGs = 3 layers x 40 col-slices(26) x 2 K-halves. Weights (6 mats x 26
// cols x 512 k) LDS-stationary. Each WG reads 256 KB of A per cell (half K)
// -> aggregate A-broadcast 61 MB/step (was 130). K-partners exchange bf16
// partials via MALL scratch and split the epilogue by rows (64 each).
__global__ __launch_bounds__(512, 2) void dgru_ksplit(
    const unsigned short* __restrict__ xbf,
    const float* __restrict__ Wih, const float* __restrict__ Whh,
    const float* __restrict__ bih, const float* __restrict__ bhh,
    unsigned short* __restrict__ ring_bf,   // [3][32][BD]
    float* __restrict__ ring_f,             // [3][32][BD]
    unsigned short* __restrict__ hin_ring,  // [2][32][BD]
    float* __restrict__ out,
    unsigned* __restrict__ prog,            // [0..383] cell flags, [512..] partial flags
    char* __restrict__ pscratch)            // [120][4 buf][2 region][PREG]
{
    __shared__ unsigned short wlds[156 * ROWL];  // 162,240 B

    const int b     = blockIdx.x;
    const int half  = b / NUNIT;            // K-half; partner at b +/- 120
    const int j     = b % NUNIT;
    const int layer = j / NSL;
    const int slice = j % NSL;
    const int ncols = (slice < NSL - 1) ? 26 : (D - 26 * (NSL - 1));  // 26 or 10
    const int c0    = slice * 26;
    const int kh0   = half * KH;

    const int tid = threadIdx.x;

    // ---- one-time: weight slice (6 mats x ncols x KH) fp32 -> bf16 -> LDS
    {
        const float* wsrc0 = Wih + (size_t)layer * 3 * D * D;
        const float* wsrc1 = Whh + (size_t)layer * 3 * D * D;
        const int nrows = 6 * ncols;
        const int rh = tid >> 7;            // 0..3
        const int t128 = tid & 127;         // 128 thr x 4 f32 = 512 k
        for (int rid = rh; rid < nrows; rid += 4) {
            int mm  = rid / (3 * ncols);    // 0=Wih, 1=Whh
            int rem = rid - mm * 3 * ncols;
            int g   = rem / ncols;
            int c   = rem - g * ncols;
            const float* src = (mm ? wsrc1 : wsrc0)
                             + ((size_t)(g * D + c0 + c)) * D + kh0 + t128 * 4;
            float4 v = *(const float4*)src;
            ushort4 o = { f2bf(v.x), f2bf(v.y), f2bf(v.z), f2bf(v.w) };
            *(ushort4*)&wlds[rid * ROWL + t128 * 4] = o;
        }
        __syncthreads();
    }

    const int wave = tid >> 6;              // 0..7, rows [wave*16, +16)
    const int lane = tid & 63;
    const int r15  = lane & 15;
    const int kq   = lane >> 4;
    const int kq8  = kq * 8;
    const bool owner = (half == 0) ? (wave < 4) : (wave >= 4);  // rows 0-63 / 64-127

    int cc[2]; bool cval[2]; int col[2];
    #pragma unroll
    for (int ct = 0; ct < 2; ++ct) {
        int c = ct * 16 + r15;
        cval[ct] = c < ncols;
        cc[ct]   = cval[ct] ? c : (ncols - 1);
        col[ct]  = c0 + cc[ct];
    }

    float bs0[2], bs1[2], bi2c[2], bh2c[2];
    #pragma unroll
    for (int ct = 0; ct < 2; ++ct) {
        bs0[ct]  = bih[layer * 3 * D + col[ct]] + bhh[layer * 3 * D + col[ct]];
        bs1[ct]  = bih[layer * 3 * D + D + col[ct]] + bhh[layer * 3 * D + D + col[ct]];
        bi2c[ct] = bih[layer * 3 * D + 2 * D + col[ct]];
        bh2c[ct] = bhh[layer * 3 * D + 2 * D + col[ct]];
    }

    // B pointers: m 0..2 = Wih gates (A=hin), 3..5 = Whh gates (A=hprev)
    const unsigned short* bpL[6][2];
    #pragma unroll
    for (int m = 0; m < 6; ++m)
        #pragma unroll
        for (int ct = 0; ct < 2; ++ct)
            bpL[m][ct] = wlds + (size_t)(m * ncols + cc[ct]) * ROWL + kq8;

    const int aoff = (wave * 16 + r15) * D + kh0 + kq8;
    const int dil  = 1 << layer;

    unsigned* pr0 = prog;
    unsigned* pr1 = prog + 128;
    unsigned* pr2 = prog + 256;
    unsigned* myflag     = prog + layer * 128 + slice * 2 + half;
    unsigned* pflag_mine = prog + 512 + j * 2 + half;
    unsigned* pflag_peer = prog + 512 + j * 2 + (1 - half);

    char* unit_base = pscratch + (size_t)j * (8 * PREG);
    const int blk = ((wave & 3) * 64 + lane) * PBLK;

    const int j2 = (lane < 16) ? lane + 64 : lane;  // cover 80 flags/layer

    for (int t = 0; t < TT; ++t) {
        int th1, th2, th3; unsigned *a1, *a2, *a3;
        if (layer == 0)      { a1 = pr0; th1 = t;     a2 = pr1; th2 = t - 30; a3 = pr2; th3 = 0;      }
        else if (layer == 1) { a1 = pr0; th1 = t + 1; a2 = pr1; th2 = t - 1;  a3 = pr2; th3 = t - 30; }
        else                 { a1 = pr1; th1 = t + 1; a2 = pr2; th2 = t - 3;  a3 = pr2; th3 = 0;      }

        if (wave == 0) {
            for (;;) {
                bool ok = true;
                if (th1 > 0) ok = ok && (int)AGLD(a1 + lane) >= th1 && (int)AGLD(a1 + j2) >= th1;
                if (th2 > 0) ok = ok && (int)AGLD(a2 + lane) >= th2 && (int)AGLD(a2 + j2) >= th2;
                if (th3 > 0) ok = ok && (int)AGLD(a3 + lane) >= th3 && (int)AGLD(a3 + j2) >= th3;
                if (__all(ok)) break;
                __builtin_amdgcn_s_sleep(1);
            }
            if ((t & 15) == 0)
                __builtin_amdgcn_fence(__ATOMIC_ACQUIRE, "agent");  // 16 < 32 - dil
        }
        __syncthreads();

        const unsigned short* hinb = layer ? hin_ring + (size_t)((layer - 1) * 32 + (t & 31)) * BD
                                           : xbf + (size_t)t * BD;
        const int rs = (t + 32 - dil) & 31, wsl = t & 31;
        const unsigned short* hprevb = ring_bf + (size_t)(layer * 32 + rs) * BD;
        const float*  hprevf = ring_f + (size_t)(layer * 32 + rs) * BD;
        float*        houtf  = ring_f + (size_t)(layer * 32 + wsl) * BD;
        unsigned short* houtb = ring_bf + (size_t)(layer * 32 + wsl) * BD;

        const int buf = t & 3;
        ull* wptr = (ull*)(unit_base + (size_t)(buf * 2 + (1 - half)) * PREG + blk);
        const ull* rptr = (const ull*)(unit_base + (size_t)(buf * 2 + half) * PREG + blk);

        // ---- epilogue operand prefetch (owners only)
        float hpv[2][4], rsv[2][4];
        if (owner) {
            #pragma unroll
            for (int ct = 0; ct < 2; ++ct)
                #pragma unroll
                for (int q = 0; q < 4; ++q) {
                    const int row = wave * 16 + kq * 4 + q;
                    const size_t idx = (size_t)row * D + col[ct];
                    hpv[ct][q] = hprevf[idx];
                    rsv[ct][q] = bf2f(hinb[idx]);
                }
        }

        f32x4 acc[2][6] = {};
        bf16x8 A0[8], A1[8], A2[8];

#define ISSUE1(Av, KS, SL) { \
        Av[(SL) * 2 + 0] = *(const bf16x8*)(hinb   + aoff + (KS) * 32); \
        Av[(SL) * 2 + 1] = *(const bf16x8*)(hprevb + aoff + (KS) * 32); }
#define ISSUEG(Av, BASE) { ISSUE1(Av, (BASE) + 0, 0) ISSUE1(Av, (BASE) + 1, 1) \
                           ISSUE1(Av, (BASE) + 2, 2) ISSUE1(Av, (BASE) + 3, 3) SB; }
#define COMPG(Av, BASE) { _Pragma("unroll") for (int kk = 0; kk < 4; ++kk) { \
        bf16x8 Bv[12]; \
        _Pragma("unroll") for (int m = 0; m < 6; ++m) { \
            Bv[m * 2 + 0] = *(const bf16x8*)(bpL[m][0] + ((BASE) + kk) * 32); \
            Bv[m * 2 + 1] = *(const bf16x8*)(bpL[m][1] + ((BASE) + kk) * 32); } \
        bf16x8 ah = Av[kk * 2 + 0], ap = Av[kk * 2 + 1]; \
        _Pragma("unroll") for (int m = 0; m < 6; ++m) { \
            acc[0][m] = MF(m < 3 ? ah : ap, Bv[m * 2 + 0], acc[0][m]); \
            acc[1][m] = MF(m < 3 ? ah : ap, Bv[m * 2 + 1], acc[1][m]); } } \
        SB; }

        // 16 ksteps (K-half), 3-deep pipeline of 4-kstep groups
        ISSUEG(A0, 0);  ISSUEG(A1, 4);  ISSUEG(A2, 8);
        COMPG(A0, 0);   ISSUEG(A0, 12);
        COMPG(A1, 4);
        COMPG(A2, 8);
        COMPG(A0, 12);

        // ---- partial exchange: non-owners pack + store bf16 partials (8B agent stores)
        if (!owner) {
            #pragma unroll
            for (int ct = 0; ct < 2; ++ct)
                #pragma unroll
                for (int m = 0; m < 6; ++m) {
                    ull w = (ull)f2bf(acc[ct][m][0])
                          | ((ull)f2bf(acc[ct][m][1]) << 16)
                          | ((ull)f2bf(acc[ct][m][2]) << 32)
                          | ((ull)f2bf(acc[ct][m][3]) << 48);
                    AGST(wptr + (ct * 6 + m), w);
                }
            asm volatile("s_waitcnt vmcnt(0)");
        }
        __syncthreads();
        if (tid == 0) {
            __builtin_amdgcn_fence(__ATOMIC_RELEASE, "agent");
            AGST(pflag_mine, (unsigned)(t + 1));
        }

        if (owner) {
            while ((int)AGLD(pflag_peer) < t + 1) __builtin_amdgcn_s_sleep(1);
            SB;
            ull pv[12];
            #pragma unroll
            for (int i = 0; i < 12; ++i) pv[i] = AGLD(rptr + i);
            SB;
            #pragma unroll
            for (int ct = 0; ct < 2; ++ct)
                #pragma unroll
                for (int m = 0; m < 6; ++m) {
                    ull w = pv[ct * 6 + m];
                    acc[ct][m][0] += bf2f((unsigned short)(w & 0xffffu));
                    acc[ct][m][1] += bf2f((unsigned short)((w >> 16) & 0xffffu));
                    acc[ct][m][2] += bf2f((unsigned short)((w >> 32) & 0xffffu));
                    acc[ct][m][3] += bf2f((unsigned short)(w >> 48));
                }

            // ---- gates + residual for owned 64 rows; sc1 stores
            #pragma unroll
            for (int ct = 0; ct < 2; ++ct)
                #pragma unroll
                for (int q = 0; q < 4; ++q) {
                    const int row = wave * 16 + kq * 4 + q;
                    const size_t idx = (size_t)row * D + col[ct];
                    float xr = acc[ct][0][q] + acc[ct][3][q] + bs0[ct];
                    float xz = acc[ct][1][q] + acc[ct][4][q] + bs1[ct];
                    float rg = 1.f / (1.f + __expf(-xr));
                    float zg = 1.f / (1.f + __expf(-xz));
                    float ng = tanhf(acc[ct][2][q] + bi2c[ct] + rg * (acc[ct][5][q] + bh2c[ct]));
                    float h  = (1.f - zg) * ng + zg * hpv[ct][q];
                    float v = (h + rsv[ct][q]) * 0.70710678f;
                    float y = v > 0.f ? v : 0.2f * v;
                    if (cval[ct]) {
                        AGST(&houtf[idx], h);
                        AGST(&houtb[idx], f2bf(h));
                        if (layer == 2) {
                            AGST(&out[(size_t)t * BD + idx], y);
                        } else {
                            AGST(&hin_ring[(size_t)(layer * 32 + (t & 31)) * BD + idx], f2bf(y));
                        }
                    }
                }
            asm volatile("s_waitcnt vmcnt(0)");
        }
        __syncthreads();
        if (tid == 0) {
            __builtin_amdgcn_fence(__ATOMIC_RELEASE, "agent");
            AGST(myflag, (unsigned)(t + 1));
        }
    }
}

extern "C" void kernel_launch(void* const* d_in, const int* in_sizes, int n_in,
                              void* d_out, int out_size, void* d_ws, size_t ws_size,
                              hipStream_t stream) {
    const float* x   = (const float*)d_in[0];
    const float* Wih = (const float*)d_in[1];
    const float* Whh = (const float*)d_in[2];
    const float* bih = (const float*)d_in[3];
    const float* bhh = (const float*)d_in[4];
    float* out = (float*)d_out;

    char* ws = (char*)d_ws;
    size_t off = 0;
    auto alloc = [&](size_t bytes) -> void* {
        void* p = ws + off;
        off += (bytes + 255) & ~(size_t)255;
        return p;
    };

    const int NX = TT * BD;
    unsigned short* xbf = (unsigned short*)alloc((size_t)NX * 2);            // 67 MB
    char* pscratch      = (char*)alloc((size_t)NUNIT * 8 * PREG);            // 23.6 MB

    size_t zstart = off;
    unsigned short* ring_bf  = (unsigned short*)alloc((size_t)96 * BD * 2);  // 25 MB
    float*          ring_f   = (float*)alloc((size_t)96 * BD * 4);           // 50 MB
    unsigned short* hin_ring = (unsigned short*)alloc((size_t)64 * BD * 2);  // 17 MB
    unsigned*       prog     = (unsigned*)alloc(4096);
    size_t zbytes = off - zstart;

    cvt_f32_bf16<<<NX / 8 / 256, 256, 0, stream>>>(x, xbf, NX);
    hipMemsetAsync(ws + zstart, 0, zbytes, stream);

    dgru_ksplit<<<NWG, 512, 0, stream>>>(
        xbf, Wih, Whh, bih, bhh,
        ring_bf, ring_f, hin_ring, out,
        prog, pscratch);
}

// Round 18
// 5609.596 us; speedup vs baseline: 3.6009x; 1.4789x over previous
//
#include <hip/hip_runtime.h>
#include <hip/hip_bf16.h>

#define TT 256
#define D 1024
#define BD (128 * 1024)
#define NWPL 85
#define NWG 256
#define NUSED 255
#define ROWLEN 1048

typedef __attribute__((ext_vector_type(8))) short bf16x8;
typedef __attribute__((ext_vector_type(4))) float f32x4;

__device__ __forceinline__ unsigned short f2bf(float f) {
    __hip_bfloat16 h = __float2bfloat16(f);
    return *reinterpret_cast<unsigned short*>(&h);
}
__device__ __forceinline__ float bf2f(unsigned short u) {
    unsigned v = (unsigned)u << 16;
    return __builtin_bit_cast(float, v);
}

__global__ __launch_bounds__(256) void cvt_f32_bf16(const float* __restrict__ in,
                                                    unsigned short* __restrict__ out, int n) {
    int i = (blockIdx.x * 256 + threadIdx.x) * 8;
    if (i + 8 <= n) {
        float4 a = *(const float4*)(in + i);
        float4 b = *(const float4*)(in + i + 4);
        unsigned short t[8] = { f2bf(a.x), f2bf(a.y), f2bf(a.z), f2bf(a.w),
                                f2bf(b.x), f2bf(b.y), f2bf(b.z), f2bf(b.w) };
        *(uint4*)(out + i) = *(const uint4*)t;
    }
}

// Persistent point-to-point dataflow dilated-GRU, 8 waves/WG (2 waves/SIMD TLP).
// Wave w handles rows [w*16, w*16+16). Rings 32 slots; acquire fence every 16
// steps (16 < 32 - dil => stale lines always invalidated between reuses).
// == Round-10 configuration: measured optimum (5.54 ms) across 13 structural
// variants; the A-operand broadcast (255 WGs x 512 KB/step at ~5.5 TB/s MALL
// service) is the established ceiling for this decomposition.
__global__ __launch_bounds__(512, 2) void dgru_dataflow(
    const unsigned short* __restrict__ xbf,
    const float* __restrict__ Wih, const float* __restrict__ Whh,
    const float* __restrict__ bih, const float* __restrict__ bhh,
    unsigned short* __restrict__ ring_bf,   // [3][32][BD]
    float* __restrict__ ring_f,             // [3][32][BD]
    unsigned short* __restrict__ hin_ring,  // [2][32][BD]
    float* __restrict__ out,
    unsigned* __restrict__ prog)
{
    __shared__ unsigned short wlds[78 * ROWLEN];

    const int grp = blockIdx.x & 7;
    const int p = 32 * grp + (blockIdx.x >> 3);  // XCD-packing heuristic (perf only)
    if (p >= NUSED) return;
    const int layer = p / NWPL;
    const int u     = p % NWPL;
    const int ncols = (u < 4) ? 13 : 12;
    const int c0    = u * 12 + (u < 4 ? u : 4);

    const int tid = threadIdx.x;

    // ---- one-time: weight slice fp32 -> bf16 -> LDS (stationary); 512 threads
    {
        const float* w0 = Wih + (size_t)layer * 3 * D * D;
        const float* w1 = Whh + (size_t)layer * 3 * D * D;
        const int nrows = 6 * ncols;
        const int rh   = tid >> 8;      // 0..1
        const int t255 = tid & 255;
        for (int rid = rh; rid < nrows; rid += 2) {
            int m   = rid / (3 * ncols);
            int rem = rid - m * 3 * ncols;
            int g   = rem / ncols;
            int c   = rem - g * ncols;
            const float* src = (m ? w1 : w0) + ((size_t)g * D + c0 + c) * D + t255 * 4;
            float4 v = *(const float4*)src;
            ushort4 o = { f2bf(v.x), f2bf(v.y), f2bf(v.z), f2bf(v.w) };
            *(ushort4*)&wlds[rid * ROWLEN + t255 * 4] = o;
        }
        __syncthreads();
    }

    const int wave = tid >> 6;          // 0..7, rows [wave*16, wave*16+16)
    const int lane = tid & 63;
    const int r15  = lane & 15;
    const int kq   = lane >> 4;
    const int kq8  = kq * 8;
    const int c_cl = (r15 < ncols) ? r15 : (ncols - 1);
    const bool cvalid = r15 < ncols;
    const int col  = c0 + c_cl;

    const float bi2 = bih[layer * 3 * D + 2 * D + col];
    const float bh2 = bhh[layer * 3 * D + 2 * D + col];
    const float bs0 = bih[layer * 3 * D + col] + bhh[layer * 3 * D + col];
    const float bs1 = bih[layer * 3 * D + D + col] + bhh[layer * 3 * D + D + col];

    const unsigned short* bp[6];
    #pragma unroll
    for (int mg = 0; mg < 6; ++mg) bp[mg] = wlds + (mg * ncols + c_cl) * ROWLEN;

    const int arow_off = (wave * 16 + r15) * D;

    const int dil = 1 << layer;

    unsigned* pr0 = prog;
    unsigned* pr1 = prog + 128;
    unsigned* pr2 = prog + 256;
    unsigned* myflag = prog + layer * 128 + u;

    const int j2 = (lane < 21) ? lane + 64 : lane;   // lanes cover flags [0,85) x2

    for (int t = 0; t < TT; ++t) {
        // thresholds: hin-ready / hprev-ready / 32-slot back-pressure
        int th1, th2, th3; unsigned *a1, *a2, *a3;
        if (layer == 0)      { a1 = pr0; th1 = t;     a2 = pr1; th2 = t - 30; a3 = pr2; th3 = 0;      }
        else if (layer == 1) { a1 = pr0; th1 = t + 1; a2 = pr1; th2 = t - 1;  a3 = pr2; th3 = t - 30; }
        else                 { a1 = pr1; th1 = t + 1; a2 = pr2; th2 = t - 3;  a3 = pr2; th3 = 0;      }

        if (wave == 0) {
            for (;;) {
                bool ok = true;
                if (th1 > 0) ok = ok && (int)__hip_atomic_load(a1 + lane, __ATOMIC_RELAXED, __HIP_MEMORY_SCOPE_AGENT) >= th1
                                     && (int)__hip_atomic_load(a1 + j2,   __ATOMIC_RELAXED, __HIP_MEMORY_SCOPE_AGENT) >= th1;
                if (th2 > 0) ok = ok && (int)__hip_atomic_load(a2 + lane, __ATOMIC_RELAXED, __HIP_MEMORY_SCOPE_AGENT) >= th2
                                     && (int)__hip_atomic_load(a2 + j2,   __ATOMIC_RELAXED, __HIP_MEMORY_SCOPE_AGENT) >= th2;
                if (th3 > 0) ok = ok && (int)__hip_atomic_load(a3 + lane, __ATOMIC_RELAXED, __HIP_MEMORY_SCOPE_AGENT) >= th3
                                     && (int)__hip_atomic_load(a3 + j2,   __ATOMIC_RELAXED, __HIP_MEMORY_SCOPE_AGENT) >= th3;
                if (__all(ok)) break;
                __builtin_amdgcn_s_sleep(1);
            }
            if ((t & 15) == 0)
                __builtin_amdgcn_fence(__ATOMIC_ACQUIRE, "agent");
        }
        __syncthreads();

        const unsigned short* hinb = layer ? hin_ring + (size_t)((layer - 1) * 32 + (t & 31)) * BD
                                           : xbf + (size_t)t * BD;
        const int rs = (t + 32 - dil) & 31, wsl = t & 31;
        const unsigned short* hprevb = ring_bf + (size_t)(layer * 32 + rs) * BD;
        const float*  hprevf = ring_f + (size_t)(layer * 32 + rs) * BD;
        float*        houtf  = ring_f + (size_t)(layer * 32 + wsl) * BD;
        unsigned short* houtb = ring_bf + (size_t)(layer * 32 + wsl) * BD;

        // ---- epilogue operand prefetch
        float hpv[4], rsv[4];
        #pragma unroll
        for (int q = 0; q < 4; ++q) {
            const int row = wave * 16 + kq * 4 + q;
            const size_t idx = (size_t)row * D + col;
            hpv[q] = hprevf[idx];
            rsv[q] = bf2f(hinb[idx]);
        }

        f32x4 acc[2][3] = {};
        bf16x8 A0[8], A1[8], A2[8];

#define ISSUE1(Av, KS, SL) { \
        Av[(SL) * 2 + 0] = *(const bf16x8*)(hinb   + arow_off + (KS) * 32 + kq8); \
        Av[(SL) * 2 + 1] = *(const bf16x8*)(hprevb + arow_off + (KS) * 32 + kq8); }
#define ISSUEG(Av, BASE) { ISSUE1(Av, (BASE) + 0, 0) ISSUE1(Av, (BASE) + 1, 1) \
                           ISSUE1(Av, (BASE) + 2, 2) ISSUE1(Av, (BASE) + 3, 3) \
                           __builtin_amdgcn_sched_barrier(0); }
#define COMPG(Av, BASE) { _Pragma("unroll") for (int kk = 0; kk < 4; ++kk) { \
        bf16x8 Bv[6]; \
        _Pragma("unroll") for (int mg = 0; mg < 6; ++mg) \
            Bv[mg] = *(const bf16x8*)(bp[mg] + ((BASE) + kk) * 32 + kq8); \
        _Pragma("unroll") for (int g = 0; g < 3; ++g) { \
            acc[0][g] = __builtin_amdgcn_mfma_f32_16x16x32_bf16(Av[kk * 2 + 0], Bv[g],     acc[0][g], 0, 0, 0); \
            acc[1][g] = __builtin_amdgcn_mfma_f32_16x16x32_bf16(Av[kk * 2 + 1], Bv[3 + g], acc[1][g], 0, 0, 0); } } \
        __builtin_amdgcn_sched_barrier(0); }

        ISSUEG(A0, 0);  ISSUEG(A1, 4);  ISSUEG(A2, 8);
        COMPG(A0, 0);   ISSUEG(A0, 12);
        COMPG(A1, 4);   ISSUEG(A1, 16);
        COMPG(A2, 8);   ISSUEG(A2, 20);
        COMPG(A0, 12);  ISSUEG(A0, 24);
        COMPG(A1, 16);  ISSUEG(A1, 28);
        COMPG(A2, 20);
        COMPG(A0, 24);
        COMPG(A1, 28);

        // ---- gates + residual; sc1 stores (MALL-direct, cross-XCD coherent)
        #pragma unroll
        for (int q = 0; q < 4; ++q) {
            const int row = wave * 16 + kq * 4 + q;
            const size_t idx = (size_t)row * D + col;
            float xr = acc[0][0][q] + acc[1][0][q] + bs0;
            float xz = acc[0][1][q] + acc[1][1][q] + bs1;
            float rg = 1.f / (1.f + __expf(-xr));
            float zg = 1.f / (1.f + __expf(-xz));
            float ng = tanhf(acc[0][2][q] + bi2 + rg * (acc[1][2][q] + bh2));
            float hp = hpv[q];
            float h  = (1.f - zg) * ng + zg * hp;
            float v = (h + rsv[q]) * 0.70710678f;
            float y = v > 0.f ? v : 0.2f * v;
            if (cvalid) {
                __hip_atomic_store(&houtf[idx], h, __ATOMIC_RELAXED, __HIP_MEMORY_SCOPE_AGENT);
                __hip_atomic_store(&houtb[idx], f2bf(h), __ATOMIC_RELAXED, __HIP_MEMORY_SCOPE_AGENT);
                if (layer == 2) {
                    __hip_atomic_store(&out[(size_t)t * BD + idx], y, __ATOMIC_RELAXED, __HIP_MEMORY_SCOPE_AGENT);
                } else {
                    __hip_atomic_store(&hin_ring[(size_t)(layer * 32 + (t & 31)) * BD + idx],
                                       f2bf(y), __ATOMIC_RELAXED, __HIP_MEMORY_SCOPE_AGENT);
                }
            }
        }

        __syncthreads();  // all 8 waves drain vmcnt(0) before publish
        if (tid == 0) {
            __builtin_amdgcn_fence(__ATOMIC_RELEASE, "agent");
            __hip_atomic_store(myflag, (unsigned)(t + 1), __ATOMIC_RELAXED, __HIP_MEMORY_SCOPE_AGENT);
        }
    }
}

extern "C" void kernel_launch(void* const* d_in, const int* in_sizes, int n_in,
                              void* d_out, int out_size, void* d_ws, size_t ws_size,
                              hipStream_t stream) {
    const float* x   = (const float*)d_in[0];
    const float* Wih = (const float*)d_in[1];
    const float* Whh = (const float*)d_in[2];
    const float* bih = (const float*)d_in[3];
    const float* bhh = (const float*)d_in[4];
    float* out = (float*)d_out;

    char* ws = (char*)d_ws;
    size_t off = 0;
    auto alloc = [&](size_t bytes) -> void* {
        void* p = ws + off;
        off += (bytes + 255) & ~(size_t)255;
        return p;
    };

    const int NX = TT * BD;
    unsigned short* xbf = (unsigned short*)alloc((size_t)NX * 2);  // 67 MB

    size_t zstart = off;
    unsigned short* ring_bf  = (unsigned short*)alloc((size_t)96 * BD * 2);  // 25 MB
    float*          ring_f   = (float*)alloc((size_t)96 * BD * 4);           // 50 MB
    unsigned short* hin_ring = (unsigned short*)alloc((size_t)64 * BD * 2);  // 17 MB
    unsigned*       prog     = (unsigned*)alloc(2048);
    size_t zbytes = off - zstart;

    cvt_f32_bf16<<<NX / 8 / 256, 256, 0, stream>>>(x, xbf, NX);
    hipMemsetAsync(ws + zstart, 0, zbytes, stream);

    dgru_dataflow<<<NWG, 512, 0, stream>>>(
        xbf, Wih, Whh, bih, bhh,
        ring_bf, ring_f, hin_ring, out,
        prog);
}